// Round 6
// baseline (197.155 us; speedup 1.0000x reference)
//
#include <hip/hip_runtime.h>
#include <hip/hip_bf16.h>

#define SS 8192
#define DD 2048
#define EE 64
#define CAP 128
// combine_weights size = SS*EE*CAP
#define SEC (67108864LL)

typedef float floatx4 __attribute__((ext_vector_type(4)));

__device__ __forceinline__ float bcast(float v, int lane) {
    return __builtin_bit_cast(float,
        __builtin_amdgcn_readlane(__builtin_bit_cast(int, v), lane));
}

// ---------------------------------------------------------------------------
// Kernel 1: fused {zero-fill of 537 MB output} + {gate GEMM/softmax/argmax}.
// Blocks 0..511   : gate (readlane-broadcast FMA, ~35us total, hides under fill).
// Blocks 512..8703: fill. Each block zeroes one contiguous 64 KB chunk with
//                   PLAIN 16B stores (r5 used nontemporal; all d_out writers
//                   cap at ~4.1-4.8 TB/s and NT looked like the low end --
//                   this round isolates that variable).
// ---------------------------------------------------------------------------
__global__ __launch_bounds__(256) void k_fill_gate(const float* __restrict__ x,
                                                   const float* __restrict__ wg,
                                                   float* __restrict__ out,
                                                   int* __restrict__ idx_out,
                                                   float* __restrict__ gval_out,
                                                   float* __restrict__ gpart) {
    if (blockIdx.x >= 512) {
        // ---- fill path: block owns 16B-elem range [fb*4096, (fb+1)*4096) ----
        const int fb = blockIdx.x - 512;  // 0..8191
        floatx4* __restrict__ out4 = (floatx4*)out;
        const size_t base = (size_t)fb * 4096 + threadIdx.x;
        const floatx4 z = {0.f, 0.f, 0.f, 0.f};
#pragma unroll
        for (int k = 0; k < 16; ++k)
            out4[base + (size_t)k * 256] = z;   // plain global_store_dwordx4
        if (fb == 0 && threadIdx.x == 0) out[2 * SEC] = 0.f;  // tail element
        return;
    }

    // ---- gate path ----
    const int bid = blockIdx.x;  // 0..511
    const int lane = threadIdx.x & 63;
    const int wv = __builtin_amdgcn_readfirstlane(threadIdx.x >> 6); // 0..3
    const int tg = wv >> 1;   // token group within block
    const int dh = wv & 1;    // D half
    const int tokBase = bid * 16 + tg * 8;
    const float* xp = x + (size_t)tokBase * DD + dh * 1024;
    const float* wp = wg + (size_t)dh * 1024 * EE + lane;

    float acc[8] = {0.f, 0.f, 0.f, 0.f, 0.f, 0.f, 0.f, 0.f};

    // 16 batches of 64 k-values each (covers this wave's 1024-deep D half)
    for (int b = 0; b < 16; ++b) {
        float xv[8];
#pragma unroll
        for (int t = 0; t < 8; ++t)
            xv[t] = xp[(size_t)t * DD + b * 64 + lane];  // coalesced 256B

#pragma unroll
        for (int g = 0; g < 4; ++g) {
            float w[16];
#pragma unroll
            for (int j = 0; j < 16; ++j)
                w[j] = wp[(size_t)(b * 64 + g * 16 + j) * EE];  // coalesced
#pragma unroll
            for (int j = 0; j < 16; ++j) {
#pragma unroll
                for (int t = 0; t < 8; ++t)
                    acc[t] = fmaf(bcast(xv[t], g * 16 + j), w[j], acc[t]);
            }
        }
    }

    // combine the two D-halves through LDS
    __shared__ float part[4][8][64];
#pragma unroll
    for (int t = 0; t < 8; ++t) part[wv][t][lane] = acc[t];
    __syncthreads();

    __shared__ float gshare[2][64];
    if (dh == 0) {
        float gs = 0.f;
#pragma unroll
        for (int t = 0; t < 8; ++t) {
            float v = part[wv][t][lane] + part[wv + 1][t][lane];
            // argmax over lanes, first-index tie rule (matches jnp.argmax)
            float m = v;
            int mi = lane;
#pragma unroll
            for (int off = 1; off < 64; off <<= 1) {
                float ov = __shfl_xor(m, off);
                int oi = __shfl_xor(mi, off);
                if (ov > m || (ov == m && oi < mi)) { m = ov; mi = oi; }
            }
            float p = __expf(v - m);
            float s = p;
#pragma unroll
            for (int off = 1; off < 64; off <<= 1) s += __shfl_xor(s, off);
            gs += p / s;  // gates[tok][lane], accumulated per expert(=lane)
            if (lane == 0) {
                idx_out[tokBase + t] = mi;
                gval_out[tokBase + t] = 1.0f / s;  // gate value of argmax expert
            }
        }
        gshare[tg][lane] = gs;
    }
    __syncthreads();
    if (wv == 0) {
        gpart[(size_t)bid * 64 + lane] = gshare[0][lane] + gshare[1][lane];
    }
}

// ---------------------------------------------------------------------------
// Kernel 2: per-expert rank (prefix count over token order) + scatter of
// combine_weights / dispatch_mask nonzeros. One block per expert.
// ---------------------------------------------------------------------------
__global__ __launch_bounds__(256) void k_scatter(const int* __restrict__ idx,
                                                 const float* __restrict__ gval,
                                                 float* __restrict__ out,
                                                 int* __restrict__ counts) {
    const int e = blockIdx.x;
    const int tid = threadIdx.x;
    const int lane = tid & 63;
    const int wv = tid >> 6;

    __shared__ int wtot[4];
    int running = 0;

    for (int s0 = 0; s0 < SS; s0 += 256) {
        const int s = s0 + tid;
        const bool flag = (idx[s] == e);
        unsigned long long mask = __ballot(flag);
        int excl = __popcll(mask & ((1ULL << lane) - 1ULL));
        int wt = __popcll(mask);
        if (lane == 0) wtot[wv] = wt;
        __syncthreads();
        int pre = 0;
#pragma unroll
        for (int w2 = 0; w2 < 4; ++w2)
            if (w2 < wv) pre += wtot[w2];
        const int blockTot = wtot[0] + wtot[1] + wtot[2] + wtot[3];
        const int rank = running + pre + excl;
        if (flag && rank < CAP) {
            const size_t o = (size_t)s * (EE * CAP) + (size_t)e * CAP + rank;
            out[1 + o] = gval[s];                 // combine_weights
            out[1 + (size_t)SEC + o] = 1.0f;      // dispatch_mask
        }
        running += blockTot;
        __syncthreads();
    }
    if (tid == 0) counts[e] = running;  // pre-drop count (ce uses pre-drop mask)
}

// ---------------------------------------------------------------------------
// Kernel 3: l_aux = E/S^2 * sum_e gatesum[e] * count[e]  -> d_out[0]
// ---------------------------------------------------------------------------
__global__ __launch_bounds__(1024) void k_laux(const float* __restrict__ gpart,
                                               const int* __restrict__ counts,
                                               float* __restrict__ out) {
    const int lane = threadIdx.x & 63;
    const int stripe = threadIdx.x >> 6;  // 0..15
    float s = 0.f;
    for (int b = stripe; b < 512; b += 16) s += gpart[(size_t)b * 64 + lane];
    __shared__ float red[16][64];
    red[stripe][lane] = s;
    __syncthreads();
    if (threadIdx.x < 64) {
        float gsum = 0.f;
#pragma unroll
        for (int r = 0; r < 16; ++r) gsum += red[r][lane];
        float term = gsum * (float)counts[lane];
#pragma unroll
        for (int off = 1; off < 64; off <<= 1) term += __shfl_xor(term, off);
        if (lane == 0)
            out[0] = term * ((float)EE / ((float)SS * (float)SS));
    }
}

extern "C" void kernel_launch(void* const* d_in, const int* in_sizes, int n_in,
                              void* d_out, int out_size, void* d_ws, size_t ws_size,
                              hipStream_t stream) {
    const float* x = (const float*)d_in[0];
    const float* wg = (const float*)d_in[1];
    float* out = (float*)d_out;

    // workspace layout (floats): idx[8192] | gval[8192] | gpart[512*64] | counts[64]
    int* idxp = (int*)d_ws;
    float* gval = (float*)d_ws + SS;
    float* gpart = (float*)d_ws + 2 * SS;
    int* counts = (int*)d_ws + 2 * SS + 512 * 64;

    // fused fill (blocks 512..8703) + gate (blocks 0..511)
    hipLaunchKernelGGL(k_fill_gate, dim3(8704), dim3(256), 0, stream,
                       x, wg, out, idxp, gval, gpart);
    hipLaunchKernelGGL(k_scatter, dim3(64), dim3(256), 0, stream, idxp, gval, out, counts);
    hipLaunchKernelGGL(k_laux, dim3(1), dim3(1024), 0, stream, gpart, counts, out);
}

// Round 7
// 192.448 us; speedup vs baseline: 1.0245x; 1.0245x over previous
//
#include <hip/hip_runtime.h>
#include <hip/hip_bf16.h>

#define SS 8192
#define DD 2048
#define EE 64
#define CAP 128
// combine_weights size = SS*EE*CAP
#define SEC (67108864LL)

#define FILLB 4096   // fill blocks, each owns 128 KB (8192 float4)
#define GATEB 512    // gate blocks, IDs FILLB..FILLB+511

typedef float floatx4 __attribute__((ext_vector_type(4)));

__device__ __forceinline__ float bcast(float v, int lane) {
    return __builtin_bit_cast(float,
        __builtin_amdgcn_readlane(__builtin_bit_cast(int, v), lane));
}

// ---------------------------------------------------------------------------
// Kernel 1: fused {zero-fill of 537 MB output} + {gate GEMM/softmax/argmax}.
// Blocks 0..4095    : fill FIRST (saturate write pipe from t=0). Each block
//                     zeroes one contiguous 128 KB chunk with nontemporal
//                     16B stores (r6 A/B showed NT beats plain by ~35us).
// Blocks 4096..4607 : gate. Block b handles 16 tokens; readlane-broadcast
//                     FMA (r5). Gate VALU work hides under the fill.
// ---------------------------------------------------------------------------
__global__ __launch_bounds__(256) void k_fill_gate(const float* __restrict__ x,
                                                   const float* __restrict__ wg,
                                                   float* __restrict__ out,
                                                   int* __restrict__ idx_out,
                                                   float* __restrict__ gval_out,
                                                   float* __restrict__ gpart) {
    if (blockIdx.x < FILLB) {
        // ---- fill path: block owns float4 range [fb*8192, (fb+1)*8192) ----
        const int fb = blockIdx.x;
        floatx4* __restrict__ out4 = (floatx4*)out;
        const size_t base = (size_t)fb * 8192 + threadIdx.x;
        const floatx4 z = {0.f, 0.f, 0.f, 0.f};
#pragma unroll
        for (int k = 0; k < 32; ++k)
            __builtin_nontemporal_store(z, &out4[base + (size_t)k * 256]);
        if (fb == 0 && threadIdx.x == 0) out[2 * SEC] = 0.f;  // tail element
        return;
    }

    // ---- gate path ----
    const int bid = blockIdx.x - FILLB;  // 0..511
    const int lane = threadIdx.x & 63;
    const int wv = __builtin_amdgcn_readfirstlane(threadIdx.x >> 6); // 0..3
    const int tg = wv >> 1;   // token group within block
    const int dh = wv & 1;    // D half
    const int tokBase = bid * 16 + tg * 8;
    const float* xp = x + (size_t)tokBase * DD + dh * 1024;
    const float* wp = wg + (size_t)dh * 1024 * EE + lane;

    float acc[8] = {0.f, 0.f, 0.f, 0.f, 0.f, 0.f, 0.f, 0.f};

    // 16 batches of 64 k-values each (covers this wave's 1024-deep D half)
    for (int b = 0; b < 16; ++b) {
        float xv[8];
#pragma unroll
        for (int t = 0; t < 8; ++t)
            xv[t] = xp[(size_t)t * DD + b * 64 + lane];  // coalesced 256B

#pragma unroll
        for (int g = 0; g < 4; ++g) {
            float w[16];
#pragma unroll
            for (int j = 0; j < 16; ++j)
                w[j] = wp[(size_t)(b * 64 + g * 16 + j) * EE];  // coalesced
#pragma unroll
            for (int j = 0; j < 16; ++j) {
#pragma unroll
                for (int t = 0; t < 8; ++t)
                    acc[t] = fmaf(bcast(xv[t], g * 16 + j), w[j], acc[t]);
            }
        }
    }

    // combine the two D-halves through LDS
    __shared__ float part[4][8][64];
#pragma unroll
    for (int t = 0; t < 8; ++t) part[wv][t][lane] = acc[t];
    __syncthreads();

    __shared__ float gshare[2][64];
    if (dh == 0) {
        float gs = 0.f;
#pragma unroll
        for (int t = 0; t < 8; ++t) {
            float v = part[wv][t][lane] + part[wv + 1][t][lane];
            // argmax over lanes, first-index tie rule (matches jnp.argmax)
            float m = v;
            int mi = lane;
#pragma unroll
            for (int off = 1; off < 64; off <<= 1) {
                float ov = __shfl_xor(m, off);
                int oi = __shfl_xor(mi, off);
                if (ov > m || (ov == m && oi < mi)) { m = ov; mi = oi; }
            }
            float p = __expf(v - m);
            float s = p;
#pragma unroll
            for (int off = 1; off < 64; off <<= 1) s += __shfl_xor(s, off);
            gs += p / s;  // gates[tok][lane], accumulated per expert(=lane)
            if (lane == 0) {
                idx_out[tokBase + t] = mi;
                gval_out[tokBase + t] = 1.0f / s;  // gate value of argmax expert
            }
        }
        gshare[tg][lane] = gs;
    }
    __syncthreads();
    if (wv == 0) {
        gpart[(size_t)bid * 64 + lane] = gshare[0][lane] + gshare[1][lane];
    }
}

// ---------------------------------------------------------------------------
// Kernel 2: per-expert rank (prefix count over token order) + scatter of
// combine_weights / dispatch_mask nonzeros. One block per expert.
// ---------------------------------------------------------------------------
__global__ __launch_bounds__(256) void k_scatter(const int* __restrict__ idx,
                                                 const float* __restrict__ gval,
                                                 float* __restrict__ out,
                                                 int* __restrict__ counts) {
    const int e = blockIdx.x;
    const int tid = threadIdx.x;
    const int lane = tid & 63;
    const int wv = tid >> 6;

    __shared__ int wtot[4];
    int running = 0;

    for (int s0 = 0; s0 < SS; s0 += 256) {
        const int s = s0 + tid;
        const bool flag = (idx[s] == e);
        unsigned long long mask = __ballot(flag);
        int excl = __popcll(mask & ((1ULL << lane) - 1ULL));
        int wt = __popcll(mask);
        if (lane == 0) wtot[wv] = wt;
        __syncthreads();
        int pre = 0;
#pragma unroll
        for (int w2 = 0; w2 < 4; ++w2)
            if (w2 < wv) pre += wtot[w2];
        const int blockTot = wtot[0] + wtot[1] + wtot[2] + wtot[3];
        const int rank = running + pre + excl;
        if (flag && rank < CAP) {
            const size_t o = (size_t)s * (EE * CAP) + (size_t)e * CAP + rank;
            out[1 + o] = gval[s];                 // combine_weights
            out[1 + (size_t)SEC + o] = 1.0f;      // dispatch_mask
        }
        running += blockTot;
        __syncthreads();
    }
    if (tid == 0) counts[e] = running;  // pre-drop count (ce uses pre-drop mask)
}

// ---------------------------------------------------------------------------
// Kernel 3: l_aux = E/S^2 * sum_e gatesum[e] * count[e]  -> d_out[0]
// ---------------------------------------------------------------------------
__global__ __launch_bounds__(1024) void k_laux(const float* __restrict__ gpart,
                                               const int* __restrict__ counts,
                                               float* __restrict__ out) {
    const int lane = threadIdx.x & 63;
    const int stripe = threadIdx.x >> 6;  // 0..15
    float s = 0.f;
    for (int b = stripe; b < 512; b += 16) s += gpart[(size_t)b * 64 + lane];
    __shared__ float red[16][64];
    red[stripe][lane] = s;
    __syncthreads();
    if (threadIdx.x < 64) {
        float gsum = 0.f;
#pragma unroll
        for (int r = 0; r < 16; ++r) gsum += red[r][lane];
        float term = gsum * (float)counts[lane];
#pragma unroll
        for (int off = 1; off < 64; off <<= 1) term += __shfl_xor(term, off);
        if (lane == 0)
            out[0] = term * ((float)EE / ((float)SS * (float)SS));
    }
}

extern "C" void kernel_launch(void* const* d_in, const int* in_sizes, int n_in,
                              void* d_out, int out_size, void* d_ws, size_t ws_size,
                              hipStream_t stream) {
    const float* x = (const float*)d_in[0];
    const float* wg = (const float*)d_in[1];
    float* out = (float*)d_out;

    // workspace layout (floats): idx[8192] | gval[8192] | gpart[512*64] | counts[64]
    int* idxp = (int*)d_ws;
    float* gval = (float*)d_ws + SS;
    float* gpart = (float*)d_ws + 2 * SS;
    int* counts = (int*)d_ws + 2 * SS + 512 * 64;

    // fused fill (blocks 0..4095) + gate (blocks 4096..4607)
    hipLaunchKernelGGL(k_fill_gate, dim3(FILLB + GATEB), dim3(256), 0, stream,
                       x, wg, out, idxp, gval, gpart);
    hipLaunchKernelGGL(k_scatter, dim3(64), dim3(256), 0, stream, idxp, gval, out, counts);
    hipLaunchKernelGGL(k_laux, dim3(1), dim3(1024), 0, stream, gpart, counts, out);
}

// Round 8
// 175.461 us; speedup vs baseline: 1.1236x; 1.0968x over previous
//
#include <hip/hip_runtime.h>
#include <hip/hip_bf16.h>

#define SS 8192
#define DD 2048
#define EE 64
#define CAP 128
// combine_weights size = SS*EE*CAP
#define SEC (67108864LL)

typedef float floatx4 __attribute__((ext_vector_type(4)));

__device__ __forceinline__ float bcast(float v, int lane) {
    return __builtin_bit_cast(float,
        __builtin_amdgcn_readlane(__builtin_bit_cast(int, v), lane));
}

// ---------------------------------------------------------------------------
// Kernel 1 (exact r5 config -- best measured): fused {zero-fill} + {gate}.
// Blocks 0..511   : gate FIRST (overlaps under the fill; r7 showed gate-last
//                   serializes: +30us). Block b handles tokens 16b..16b+15.
//                   readlane-broadcast FMA gate (r5).
// Blocks 512..8703: fill. Each block zeroes one contiguous 64 KB chunk with
//                   nontemporal 16B stores (r6 A/B: NT beats plain by ~35us).
// ---------------------------------------------------------------------------
__global__ __launch_bounds__(256) void k_fill_gate(const float* __restrict__ x,
                                                   const float* __restrict__ wg,
                                                   float* __restrict__ out,
                                                   int* __restrict__ idx_out,
                                                   float* __restrict__ gval_out,
                                                   float* __restrict__ gpart) {
    if (blockIdx.x >= 512) {
        // ---- fill path: block owns float4 range [fb*4096, (fb+1)*4096) ----
        const int fb = blockIdx.x - 512;  // 0..8191
        floatx4* __restrict__ out4 = (floatx4*)out;
        const size_t base = (size_t)fb * 4096 + threadIdx.x;
        const floatx4 z = {0.f, 0.f, 0.f, 0.f};
#pragma unroll
        for (int k = 0; k < 16; ++k)
            __builtin_nontemporal_store(z, &out4[base + (size_t)k * 256]);
        if (fb == 0 && threadIdx.x == 0) out[2 * SEC] = 0.f;  // tail element
        return;
    }

    // ---- gate path ----
    const int bid = blockIdx.x;  // 0..511
    const int lane = threadIdx.x & 63;
    const int wv = __builtin_amdgcn_readfirstlane(threadIdx.x >> 6); // 0..3
    const int tg = wv >> 1;   // token group within block
    const int dh = wv & 1;    // D half
    const int tokBase = bid * 16 + tg * 8;
    const float* xp = x + (size_t)tokBase * DD + dh * 1024;
    const float* wp = wg + (size_t)dh * 1024 * EE + lane;

    float acc[8] = {0.f, 0.f, 0.f, 0.f, 0.f, 0.f, 0.f, 0.f};

    // 16 batches of 64 k-values each (covers this wave's 1024-deep D half)
    for (int b = 0; b < 16; ++b) {
        float xv[8];
#pragma unroll
        for (int t = 0; t < 8; ++t)
            xv[t] = xp[(size_t)t * DD + b * 64 + lane];  // coalesced 256B

#pragma unroll
        for (int g = 0; g < 4; ++g) {
            float w[16];
#pragma unroll
            for (int j = 0; j < 16; ++j)
                w[j] = wp[(size_t)(b * 64 + g * 16 + j) * EE];  // coalesced
#pragma unroll
            for (int j = 0; j < 16; ++j) {
#pragma unroll
                for (int t = 0; t < 8; ++t)
                    acc[t] = fmaf(bcast(xv[t], g * 16 + j), w[j], acc[t]);
            }
        }
    }

    // combine the two D-halves through LDS
    __shared__ float part[4][8][64];
#pragma unroll
    for (int t = 0; t < 8; ++t) part[wv][t][lane] = acc[t];
    __syncthreads();

    __shared__ float gshare[2][64];
    if (dh == 0) {
        float gs = 0.f;
#pragma unroll
        for (int t = 0; t < 8; ++t) {
            float v = part[wv][t][lane] + part[wv + 1][t][lane];
            // argmax over lanes, first-index tie rule (matches jnp.argmax)
            float m = v;
            int mi = lane;
#pragma unroll
            for (int off = 1; off < 64; off <<= 1) {
                float ov = __shfl_xor(m, off);
                int oi = __shfl_xor(mi, off);
                if (ov > m || (ov == m && oi < mi)) { m = ov; mi = oi; }
            }
            float p = __expf(v - m);
            float s = p;
#pragma unroll
            for (int off = 1; off < 64; off <<= 1) s += __shfl_xor(s, off);
            gs += p / s;  // gates[tok][lane], accumulated per expert(=lane)
            if (lane == 0) {
                idx_out[tokBase + t] = mi;
                gval_out[tokBase + t] = 1.0f / s;  // gate value of argmax expert
            }
        }
        gshare[tg][lane] = gs;
    }
    __syncthreads();
    if (wv == 0) {
        gpart[(size_t)bid * 64 + lane] = gshare[0][lane] + gshare[1][lane];
    }
}

// ---------------------------------------------------------------------------
// Kernel 2: merged scatter + l_aux, one dispatch (removes a launch gap).
// Blocks 0..15 : wave-per-expert scatter. Wave w owns expert 4*blockIdx+w.
//                128 chunks of 64 tokens, __ballot/popcll rank scan --
//                fully wave-synchronous, zero __syncthreads (replaces the
//                r5 scatter's 64 blocks x 32 sync'd iterations).
// Block 16     : l_aux. Own histogram of idx (LDS atomics) + gpart reduction.
// ---------------------------------------------------------------------------
__global__ __launch_bounds__(256) void k_scatter_laux(const int* __restrict__ idx,
                                                      const float* __restrict__ gval,
                                                      const float* __restrict__ gpart,
                                                      float* __restrict__ out) {
    const int tid = threadIdx.x;
    const int lane = tid & 63;
    const int wv = tid >> 6;

    if (blockIdx.x < 16) {
        const int e = blockIdx.x * 4 + wv;  // this wave's expert
        int running = 0;
        for (int c = 0; c < 128; ++c) {
            const int s = c * 64 + lane;
            const bool flag = (idx[s] == e);
            const unsigned long long mask = __ballot(flag);
            const int rank = running + __popcll(mask & ((1ULL << lane) - 1ULL));
            if (flag && rank < CAP) {
                const size_t o = (size_t)s * (EE * CAP) + (size_t)e * CAP + rank;
                out[1 + o] = gval[s];                 // combine_weights
                out[1 + (size_t)SEC + o] = 1.0f;      // dispatch_mask
            }
            running += __popcll(mask);
        }
        return;
    }

    // ---- l_aux block ----
    __shared__ int hist[64];
    if (tid < 64) hist[tid] = 0;
    __syncthreads();
    for (int s = tid; s < SS; s += 256) atomicAdd(&hist[idx[s]], 1);
    __syncthreads();

    float sum = 0.f;
    for (int b = wv; b < 512; b += 4) sum += gpart[(size_t)b * 64 + lane];
    __shared__ float red[4][64];
    red[wv][lane] = sum;
    __syncthreads();
    if (tid < 64) {
        float gsum = red[0][lane] + red[1][lane] + red[2][lane] + red[3][lane];
        float term = gsum * (float)hist[lane];
#pragma unroll
        for (int off = 1; off < 64; off <<= 1) term += __shfl_xor(term, off);
        if (lane == 0)
            out[0] = term * ((float)EE / ((float)SS * (float)SS));
    }
}

extern "C" void kernel_launch(void* const* d_in, const int* in_sizes, int n_in,
                              void* d_out, int out_size, void* d_ws, size_t ws_size,
                              hipStream_t stream) {
    const float* x = (const float*)d_in[0];
    const float* wg = (const float*)d_in[1];
    float* out = (float*)d_out;

    // workspace layout (floats): idx[8192] | gval[8192] | gpart[512*64]
    int* idxp = (int*)d_ws;
    float* gval = (float*)d_ws + SS;
    float* gpart = (float*)d_ws + 2 * SS;

    // fused gate (blocks 0..511) + fill (blocks 512..8703)  [r5 config]
    hipLaunchKernelGGL(k_fill_gate, dim3(8704), dim3(256), 0, stream,
                       x, wg, out, idxp, gval, gpart);
    // merged scatter (blocks 0..15) + l_aux (block 16)
    hipLaunchKernelGGL(k_scatter_laux, dim3(17), dim3(256), 0, stream,
                       idxp, gval, gpart, out);
}

// Round 9
// 168.214 us; speedup vs baseline: 1.1720x; 1.0431x over previous
//
#include <hip/hip_runtime.h>
#include <hip/hip_bf16.h>

#define SS 8192
#define DD 2048
#define EE 64
#define CAP 128
// combine_weights size = SS*EE*CAP
#define SEC (67108864LL)

typedef float floatx4 __attribute__((ext_vector_type(4)));

__device__ __forceinline__ float bcast(float v, int lane) {
    return __builtin_bit_cast(float,
        __builtin_amdgcn_readlane(__builtin_bit_cast(int, v), lane));
}

// ---------------------------------------------------------------------------
// Kernel 1 (exact r5 config -- best measured): fused {zero-fill} + {gate}.
// Blocks 0..511   : gate FIRST (r7 A/B: gate-last serializes, +30us).
// Blocks 512..8703: fill, 64 KB NT chunks (r6 A/B: NT beats plain by ~35us).
// ---------------------------------------------------------------------------
__global__ __launch_bounds__(256) void k_fill_gate(const float* __restrict__ x,
                                                   const float* __restrict__ wg,
                                                   float* __restrict__ out,
                                                   int* __restrict__ idx_out,
                                                   float* __restrict__ gval_out,
                                                   float* __restrict__ gpart) {
    if (blockIdx.x >= 512) {
        // ---- fill path: block owns float4 range [fb*4096, (fb+1)*4096) ----
        const int fb = blockIdx.x - 512;  // 0..8191
        floatx4* __restrict__ out4 = (floatx4*)out;
        const size_t base = (size_t)fb * 4096 + threadIdx.x;
        const floatx4 z = {0.f, 0.f, 0.f, 0.f};
#pragma unroll
        for (int k = 0; k < 16; ++k)
            __builtin_nontemporal_store(z, &out4[base + (size_t)k * 256]);
        if (fb == 0 && threadIdx.x == 0) out[2 * SEC] = 0.f;  // tail element
        return;
    }

    // ---- gate path ----
    const int bid = blockIdx.x;  // 0..511
    const int lane = threadIdx.x & 63;
    const int wv = __builtin_amdgcn_readfirstlane(threadIdx.x >> 6); // 0..3
    const int tg = wv >> 1;   // token group within block
    const int dh = wv & 1;    // D half
    const int tokBase = bid * 16 + tg * 8;
    const float* xp = x + (size_t)tokBase * DD + dh * 1024;
    const float* wp = wg + (size_t)dh * 1024 * EE + lane;

    float acc[8] = {0.f, 0.f, 0.f, 0.f, 0.f, 0.f, 0.f, 0.f};

    // 16 batches of 64 k-values each (covers this wave's 1024-deep D half)
    for (int b = 0; b < 16; ++b) {
        float xv[8];
#pragma unroll
        for (int t = 0; t < 8; ++t)
            xv[t] = xp[(size_t)t * DD + b * 64 + lane];  // coalesced 256B

#pragma unroll
        for (int g = 0; g < 4; ++g) {
            float w[16];
#pragma unroll
            for (int j = 0; j < 16; ++j)
                w[j] = wp[(size_t)(b * 64 + g * 16 + j) * EE];  // coalesced
#pragma unroll
            for (int j = 0; j < 16; ++j) {
#pragma unroll
                for (int t = 0; t < 8; ++t)
                    acc[t] = fmaf(bcast(xv[t], g * 16 + j), w[j], acc[t]);
            }
        }
    }

    // combine the two D-halves through LDS
    __shared__ float part[4][8][64];
#pragma unroll
    for (int t = 0; t < 8; ++t) part[wv][t][lane] = acc[t];
    __syncthreads();

    __shared__ float gshare[2][64];
    if (dh == 0) {
        float gs = 0.f;
#pragma unroll
        for (int t = 0; t < 8; ++t) {
            float v = part[wv][t][lane] + part[wv + 1][t][lane];
            // argmax over lanes, first-index tie rule (matches jnp.argmax)
            float m = v;
            int mi = lane;
#pragma unroll
            for (int off = 1; off < 64; off <<= 1) {
                float ov = __shfl_xor(m, off);
                int oi = __shfl_xor(mi, off);
                if (ov > m || (ov == m && oi < mi)) { m = ov; mi = oi; }
            }
            float p = __expf(v - m);
            float s = p;
#pragma unroll
            for (int off = 1; off < 64; off <<= 1) s += __shfl_xor(s, off);
            gs += p / s;  // gates[tok][lane], accumulated per expert(=lane)
            if (lane == 0) {
                idx_out[tokBase + t] = mi;
                gval_out[tokBase + t] = 1.0f / s;  // gate value of argmax expert
            }
        }
        gshare[tg][lane] = gs;
    }
    __syncthreads();
    if (wv == 0) {
        gpart[(size_t)bid * 64 + lane] = gshare[0][lane] + gshare[1][lane];
    }
}

// ---------------------------------------------------------------------------
// Kernel 2: tail -- split-scan scatter + l_aux, one dispatch.
// Blocks 0..63 (one per expert e): wave w scans tokens [2048w, 2048w+2048).
//   Phase 1: 32 INDEPENDENT coalesced idx loads (latency overlapped), flags
//            packed into a 32-bit register, wave count via shfl reduce.
//   One __syncthreads for the wave prefix.
//   Phase 2: 32-step ballot scan from REGISTER flags (no reloads, ~10cy/step)
//            + conditional scatter stores.
// Replaces r8's 128-serial-global-load chain (~16us/block -> ~2us).
// Block 64: l_aux (idx histogram via LDS atomics + gpart reduction).
// ---------------------------------------------------------------------------
__global__ __launch_bounds__(256) void k_tail(const int* __restrict__ idx,
                                              const float* __restrict__ gval,
                                              const float* __restrict__ gpart,
                                              float* __restrict__ out) {
    const int tid = threadIdx.x;
    const int lane = tid & 63;
    const int wv = tid >> 6;

    if (blockIdx.x < 64) {
        const int e = blockIdx.x;
        const int sBase = wv * 2048;  // this wave's token segment

        // phase 1: load + flag-pack (independent loads)
        unsigned int flags = 0;
#pragma unroll
        for (int c = 0; c < 32; ++c) {
            const int s = sBase + c * 64 + lane;
            if (idx[s] == e) flags |= (1u << c);
        }
        int mycount = __popc(flags);
#pragma unroll
        for (int off = 1; off < 64; off <<= 1)
            mycount += __shfl_xor(mycount, off);

        __shared__ int wc[4];
        if (lane == 0) wc[wv] = mycount;
        __syncthreads();
        int running = 0;
        for (int w2 = 0; w2 < wv; ++w2) running += wc[w2];

        // phase 2: ballot scan from register flags
        for (int c = 0; c < 32; ++c) {
            const bool f = (flags >> c) & 1u;
            const unsigned long long mask = __ballot(f);
            const int rank = running + __popcll(mask & ((1ULL << lane) - 1ULL));
            if (f && rank < CAP) {
                const int s = sBase + c * 64 + lane;
                const size_t o = (size_t)s * (EE * CAP) + (size_t)e * CAP + rank;
                out[1 + o] = gval[s];                 // combine_weights
                out[1 + (size_t)SEC + o] = 1.0f;      // dispatch_mask
            }
            running += __popcll(mask);
        }
        return;
    }

    // ---- l_aux block (blockIdx.x == 64) ----
    __shared__ int hist[64];
    if (tid < 64) hist[tid] = 0;
    __syncthreads();
    for (int s = tid; s < SS; s += 256) atomicAdd(&hist[idx[s]], 1);
    __syncthreads();

    float sum = 0.f;
    for (int b = wv; b < 512; b += 4) sum += gpart[(size_t)b * 64 + lane];
    __shared__ float red[4][64];
    red[wv][lane] = sum;
    __syncthreads();
    if (tid < 64) {
        float gsum = red[0][lane] + red[1][lane] + red[2][lane] + red[3][lane];
        float term = gsum * (float)hist[lane];
#pragma unroll
        for (int off = 1; off < 64; off <<= 1) term += __shfl_xor(term, off);
        if (lane == 0)
            out[0] = term * ((float)EE / ((float)SS * (float)SS));
    }
}

extern "C" void kernel_launch(void* const* d_in, const int* in_sizes, int n_in,
                              void* d_out, int out_size, void* d_ws, size_t ws_size,
                              hipStream_t stream) {
    const float* x = (const float*)d_in[0];
    const float* wg = (const float*)d_in[1];
    float* out = (float*)d_out;

    // workspace layout (floats): idx[8192] | gval[8192] | gpart[512*64]
    int* idxp = (int*)d_ws;
    float* gval = (float*)d_ws + SS;
    float* gpart = (float*)d_ws + 2 * SS;

    // fused gate (blocks 0..511) + fill (blocks 512..8703)  [r5 config]
    hipLaunchKernelGGL(k_fill_gate, dim3(8704), dim3(256), 0, stream,
                       x, wg, out, idxp, gval, gpart);
    // split-scan scatter (blocks 0..63) + l_aux (block 64)
    hipLaunchKernelGGL(k_tail, dim3(65), dim3(256), 0, stream,
                       idxp, gval, gpart, out);
}